// Round 16
// baseline (285.275 us; speedup 1.0000x reference)
//
#include <hip/hip_runtime.h>
#include <hip/hip_bf16.h>

#define B_   8
#define NMAX 8192
#define C_   384
#define G_   512
#define K_   32
#define H_   6
#define DH_  64
#define CAP_ 16

typedef short bvec8 __attribute__((ext_vector_type(8)));
typedef short bvec4 __attribute__((ext_vector_type(4)));
typedef _Float16 hvec4 __attribute__((ext_vector_type(4)));
typedef float f32x4 __attribute__((ext_vector_type(4)));
typedef unsigned int u32x4 __attribute__((ext_vector_type(4)));

__device__ __forceinline__ short f2bf(float f) {
    union { __hip_bfloat16 b; short s; } u;
    u.b = __float2bfloat16(f);
    return u.s;
}

// XOR-swizzled [rows][768 B] bf16 tile (proven): colb in bytes
__device__ __forceinline__ int swzA(int row, int colb) { return row * 768 + (colb ^ ((row & 7) << 4)); }
// XOR-swizzled [rows][384 B] fp8 tile (stage buffers)
__device__ __forceinline__ int swzS(int row, int colb) { return row * 384 + (colb ^ ((row & 7) << 4)); }

// Fragment-major weight packing (proven R6/R7)
__global__ void convw_kernel(const float* __restrict__ wqkv, const float* __restrict__ wproj,
                             short* __restrict__ wq_frag, short* __restrict__ wp_frag) {
    int i = blockIdx.x * 256 + threadIdx.x;
    if (i < 55296) {
        int lane = i & 63, t = i >> 6;
        int nt = t & 3, kk = (t >> 2) % 12, hh = (t >> 2) / 12;
        int row  = hh * 64 + nt * 16 + (lane & 15);
        int col0 = kk * 32 + (lane >> 4) * 8;
        const float* src = wqkv + (size_t)row * C_ + col0;
        bvec8 v;
        #pragma unroll
        for (int e = 0; e < 8; ++e) v[e] = f2bf(src[e]);
        *(bvec8*)(wq_frag + (size_t)i * 8) = v;
    } else if (i < 55296 + 18432) {
        int j = i - 55296;
        int lane = j & 63, t = j >> 6;
        int nt = t & 3, kk = (t >> 2) % 12, h = (t >> 2) / 12;
        int row  = h * 64 + nt * 16 + (lane & 15);
        int col0 = kk * 32 + (lane >> 4) * 8;
        const float* src = wproj + (size_t)row * C_ + col0;
        bvec8 v;
        #pragma unroll
        for (int e = 0; e < 8; ++e) v[e] = f2bf(src[e]);
        *(bvec8*)(wp_frag + (size_t)j * 8) = v;
    }
}

// Inverted index: per point, list of valid slot-ids (within batch). fillcnt == cnt.
__global__ void fill_kernel(const int* __restrict__ gidx, const float* __restrict__ gmask,
                            int* __restrict__ fillcnt, unsigned short* __restrict__ list) {
    int t = blockIdx.x * 256 + threadIdx.x;
    if (t >= B_ * G_ * K_) return;
    float m = gmask[t];
    if (m <= 0.f) return;
    int v = gidx[t];
    v = v < 0 ? 0 : v;
    int b = t >> 14;
    int bn = b * NMAX + v;
    int pos = atomicAdd(&fillcnt[bn], 1);
    if (pos < CAP_) list[(size_t)bn * CAP_ + pos] = (unsigned short)(t - (b << 14));
}

// ---- Dense QKV: q/k/v fp8 = feats @ W^T, swapped-operand MFMA.
// R16: FUSED q/k/v kk-loop — each xb LDS read feeds all 3 mats (xb reads
// 3456 -> 1152 per block, the dominant LDS-BW cost). Token-half outer loop
// keeps acc at [3][2][4] = 96 VGPR. Stage 24KB per (half,mat).
#define QKV_M     128
#define QKV_STAGE (QKV_M * 768)                    // 98304
#define QKV_LDS   (QKV_M * 768 + 64 * 384)         // 122880
__global__ __launch_bounds__(768, 3) void qkv_kernel(
    const float* __restrict__ feats, const short* __restrict__ wq_frag,
    unsigned char* __restrict__ qb, unsigned char* __restrict__ kb,
    unsigned char* __restrict__ vb) {
    extern __shared__ char sm[];
    char* stage = sm + QKV_STAGE;
    const int tid  = threadIdx.x;
    const int lane = tid & 63;
    const int h2   = tid >> 6;          // wave id 0..11: head = h2>>1, dh-half = h2&1
    const int h    = h2 >> 1;
    const int mh   = h2 & 1;
    const int l15  = lane & 15;
    const int l4   = lane >> 4;
    const int pt0  = blockIdx.x * QKV_M;

    #pragma unroll
    for (int i = 0; i < 16; ++i) {
        int p = i * 768 + tid;             // 12288 f32x4 tasks
        int row = p / 96, seg = p % 96;
        f32x4 f = *(const f32x4*)(feats + (size_t)(pt0 + row) * C_ + seg * 4);
        bvec4 v4 = { f2bf(f[0]), f2bf(f[1]), f2bf(f[2]), f2bf(f[3]) };
        *(bvec4*)(sm + swzA(row, seg * 8)) = v4;
    }
    __syncthreads();

    #pragma unroll
    for (int half = 0; half < 2; ++half) {
        f32x4 acc[3][2][4];                 // [mat][dh-quarter within half][token tile]
        #pragma unroll
        for (int mat = 0; mat < 3; ++mat)
            #pragma unroll
            for (int mt = 0; mt < 2; ++mt)
                #pragma unroll
                for (int nt = 0; nt < 4; ++nt) acc[mat][mt][nt] = (f32x4){0.f, 0.f, 0.f, 0.f};

        #pragma unroll
        for (int kk = 0; kk < 12; ++kk) {
            bvec8 xb[4];
            #pragma unroll
            for (int nt = 0; nt < 4; ++nt)
                xb[nt] = *(const bvec8*)(sm + swzA(half * 64 + nt * 16 + l15, kk * 64 + l4 * 16));
            #pragma unroll
            for (int mat = 0; mat < 3; ++mat) {
                const short* wb = wq_frag + (size_t)((mat * 6 + h) * 48) * 512;
                #pragma unroll
                for (int mt = 0; mt < 2; ++mt) {
                    bvec8 wf = *(const bvec8*)(wb + (size_t)((kk * 4 + mh * 2 + mt) * 64 + lane) * 8);
                    #pragma unroll
                    for (int nt = 0; nt < 4; ++nt)
                        acc[mat][mt][nt] = __builtin_amdgcn_mfma_f32_16x16x32_bf16(wf, xb[nt], acc[mat][mt][nt], 0, 0, 0);
                }
            }
        }

        // per mat: stage this half's [64][384] fp8 rows, then coalesced copy-out
        #pragma unroll
        for (int mat = 0; mat < 3; ++mat) {
            unsigned char* dst = (mat == 0) ? qb : (mat == 1) ? kb : vb;
            // D row = dh = mh*32 + mt*16 + l4*4 + j ; col = tok-within-half = nt*16 + l15
            #pragma unroll
            for (int mt = 0; mt < 2; ++mt)
                #pragma unroll
                for (int nt = 0; nt < 4; ++nt) {
                    int w = __builtin_amdgcn_cvt_pk_fp8_f32(acc[mat][mt][nt][0], acc[mat][mt][nt][1], 0, false);
                    w = __builtin_amdgcn_cvt_pk_fp8_f32(acc[mat][mt][nt][2], acc[mat][mt][nt][3], w, true);
                    *(unsigned int*)(stage + swzS(nt * 16 + l15, h * DH_ + mh * 32 + mt * 16 + l4 * 4))
                        = (unsigned int)w;
                }
            __syncthreads();
            // copy 64 rows x 384 B: 1536 chunks of 16 B over 768 threads
            #pragma unroll
            for (int it = 0; it < 2; ++it) {
                int chunk = it * 768 + tid;
                int row = chunk / 24, off = chunk % 24;
                u32x4 v = *(const u32x4*)(stage + swzS(row, off * 16));
                *(u32x4*)(dst + (size_t)(pt0 + half * 64 + row) * C_ + off * 16) = v;
            }
            __syncthreads();   // stage reused by next mat / half
        }
    }
}

// ---- Per-group attention. SLOT=true: write PV rows (fp8) to slotbuf, NO atomics.
#define AQ_OFF   0              // 6 x [32][72] fp8 q ; also PV stage [32][384] fp8 (12288 B)
#define AK_OFF   13824          // 6 x [32][72]
#define AV_OFF   27648          // 6 x [32][68]
#define AMASK    40704
#define AIDX     40832
#define ATTN_LDS 40960

template<bool SLOT>
__global__ __launch_bounds__(384, 5) void attn2_kernel(
    const int* __restrict__ gidx, const float* __restrict__ gmask,
    const unsigned char* __restrict__ qb, const unsigned char* __restrict__ kb,
    const unsigned char* __restrict__ vb,
    unsigned char* __restrict__ slotbuf, float* __restrict__ acc_out) {
    extern __shared__ char sm[];
    float* mask_lds = (float*)(sm + AMASK);
    int*   idx_lds  = (int*)(sm + AIDX);

    const int tid  = threadIdx.x;
    const int lane = tid & 63;
    const int h    = tid >> 6;
    const int bg   = blockIdx.x;
    const int b    = bg >> 9;
    const int l15  = lane & 15;
    const int l4   = lane >> 4;

    if (tid < 32) {
        int v = gidx[(size_t)bg * K_ + tid];
        v = v < 0 ? 0 : v;
        idx_lds[tid]  = v;
        mask_lds[tid] = gmask[(size_t)bg * K_ + tid];
    }
    __syncthreads();

    char* qh = sm + AQ_OFF + h * 2304;
    char* kh = sm + AK_OFF + h * 2304;
    char* vh = sm + AV_OFF + h * 2176;

    const int t8 = lane >> 3, c8 = lane & 7;
    #pragma unroll
    for (int i = 0; i < 4; ++i) {
        int t = i * 8 + t8;
        size_t base = (size_t)(b * NMAX + idx_lds[t]) * C_ + h * DH_;
        long qv = *(const long*)(qb + base + c8 * 8);
        long kv = *(const long*)(kb + base + c8 * 8);
        long vv = *(const long*)(vb + base + c8 * 8);
        *(long*)(qh + t * 72 + c8 * 8) = qv;
        *(long*)(kh + t * 72 + c8 * 8) = kv;
        *(int*)(vh + t * 68 + c8 * 8)     = (int)(vv & 0xffffffffL);
        *(int*)(vh + t * 68 + c8 * 8 + 4) = (int)(((unsigned long)vv) >> 32);
    }

    // scores^T = k @ q^T (fp8)
    f32x4 sc[2][2];
    #pragma unroll
    for (int mt = 0; mt < 2; ++mt)
        #pragma unroll
        for (int nt = 0; nt < 2; ++nt) sc[mt][nt] = (f32x4){0.f, 0.f, 0.f, 0.f};
    #pragma unroll
    for (int kk = 0; kk < 2; ++kk) {
        long ka0 = *(const long*)(kh + l15 * 72 + kk * 32 + l4 * 8);
        long ka1 = *(const long*)(kh + (16 + l15) * 72 + kk * 32 + l4 * 8);
        long qa0 = *(const long*)(qh + l15 * 72 + kk * 32 + l4 * 8);
        long qa1 = *(const long*)(qh + (16 + l15) * 72 + kk * 32 + l4 * 8);
        sc[0][0] = __builtin_amdgcn_mfma_f32_16x16x32_fp8_fp8(ka0, qa0, sc[0][0], 0, 0, 0);
        sc[0][1] = __builtin_amdgcn_mfma_f32_16x16x32_fp8_fp8(ka0, qa1, sc[0][1], 0, 0, 0);
        sc[1][0] = __builtin_amdgcn_mfma_f32_16x16x32_fp8_fp8(ka1, qa0, sc[1][0], 0, 0, 0);
        sc[1][1] = __builtin_amdgcn_mfma_f32_16x16x32_fp8_fp8(ka1, qa1, sc[1][1], 0, 0, 0);
    }

    // softmax over keys (proven)
    float bk[2][4];
    #pragma unroll
    for (int mt = 0; mt < 2; ++mt)
        #pragma unroll
        for (int j = 0; j < 4; ++j)
            bk[mt][j] = mask_lds[mt * 16 + l4 * 4 + j] > 0.f ? 0.f : -1e30f;

    hvec4 pfrag[2][2];
    #pragma unroll
    for (int nt = 0; nt < 2; ++nt) {
        float s[2][4];
        float mx = -1e30f;
        #pragma unroll
        for (int mt = 0; mt < 2; ++mt)
            #pragma unroll
            for (int j = 0; j < 4; ++j) {
                s[mt][j] = sc[mt][nt][j] * 0.125f + bk[mt][j];
                mx = fmaxf(mx, s[mt][j]);
            }
        mx = fmaxf(mx, __shfl_xor(mx, 16));
        mx = fmaxf(mx, __shfl_xor(mx, 32));
        float sum = 0.f;
        #pragma unroll
        for (int mt = 0; mt < 2; ++mt)
            #pragma unroll
            for (int j = 0; j < 4; ++j) {
                s[mt][j] = __expf(s[mt][j] - mx);
                sum += s[mt][j];
            }
        sum += __shfl_xor(sum, 16);
        sum += __shfl_xor(sum, 32);
        float inv = 1.f / sum;
        #pragma unroll
        for (int mt = 0; mt < 2; ++mt)
            pfrag[mt][nt] = (hvec4){ (_Float16)(s[mt][0] * inv), (_Float16)(s[mt][1] * inv),
                                     (_Float16)(s[mt][2] * inv), (_Float16)(s[mt][3] * inv) };
    }

    // vfrag from LDS (fp8 -> f16)
    hvec4 vfrag[2][4];
    #pragma unroll
    for (int c = 0; c < 2; ++c)
        #pragma unroll
        for (int dt = 0; dt < 4; ++dt) {
            hvec4 vv;
            #pragma unroll
            for (int e = 0; e < 4; ++e) {
                int byt = *(const unsigned char*)(vh + (c * 16 + l4 * 4 + e) * 68 + dt * 16 + l15);
                vv[e] = (_Float16)__builtin_amdgcn_cvt_f32_fp8(byt, 0);
            }
            vfrag[c][dt] = vv;
        }

    // PV: out^T[dh][q]
    f32x4 po[4][2];
    #pragma unroll
    for (int dt = 0; dt < 4; ++dt)
        #pragma unroll
        for (int qt = 0; qt < 2; ++qt) po[dt][qt] = (f32x4){0.f, 0.f, 0.f, 0.f};
    #pragma unroll
    for (int c = 0; c < 2; ++c)
        #pragma unroll
        for (int dt = 0; dt < 4; ++dt)
            #pragma unroll
            for (int qt = 0; qt < 2; ++qt)
                po[dt][qt] = __builtin_amdgcn_mfma_f32_16x16x16f16(vfrag[c][dt], pfrag[c][qt], po[dt][qt], 0, 0, 0);

    if constexpr (SLOT) {
        // stage PV^T -> [tok][384] fp8 in the (dead) q region, then coalesced row copy
        __syncthreads();          // all waves done with their q/k LDS reads
        char* stage = sm + AQ_OFF;
        #pragma unroll
        for (int dt = 0; dt < 4; ++dt)
            #pragma unroll
            for (int qt = 0; qt < 2; ++qt) {
                int w = __builtin_amdgcn_cvt_pk_fp8_f32(po[dt][qt][0], po[dt][qt][1], 0, false);
                w = __builtin_amdgcn_cvt_pk_fp8_f32(po[dt][qt][2], po[dt][qt][3], w, true);
                *(unsigned int*)(stage + swzS(qt * 16 + l15, h * DH_ + dt * 16 + l4 * 4))
                    = (unsigned int)w;
            }
        __syncthreads();
        #pragma unroll
        for (int it = 0; it < 2; ++it) {
            int chunk = it * 384 + tid;        // 768 chunks of 16 B
            int row = chunk / 24, off = chunk % 24;
            u32x4 v = *(const u32x4*)(stage + swzS(row, off * 16));
            *(u32x4*)(slotbuf + ((size_t)bg * K_ + row) * C_ + off * 16) = v;
        }
    } else {
        #pragma unroll
        for (int qt = 0; qt < 2; ++qt) {
            int tok = qt * 16 + l15;
            float mk = mask_lds[tok];
            size_t rowb = (size_t)(b * NMAX + idx_lds[tok]) * C_ + h * DH_ + l4 * 4;
            #pragma unroll
            for (int dt = 0; dt < 4; ++dt)
                #pragma unroll
                for (int j = 0; j < 4; ++j)
                    if (mk > 0.f) atomicAdd(acc_out + rowb + dt * 16 + j, po[dt][qt][j]);
        }
    }
}

// ---- MODE A final: gather slot rows -> avg -> proj -> out. 32 points/block.
// Slot-lists staged in LDS, NT slot reads, x2 unroll (proven R13).
#define AP2_LIST (32 * 768)
#define AP2_LDS  (32 * 768 + 1024)
__global__ __launch_bounds__(384, 5) void avgproj2_kernel(
    const float* __restrict__ feats, const int* __restrict__ fillcnt,
    const unsigned short* __restrict__ list, const unsigned char* __restrict__ slotbuf,
    const short* __restrict__ wp_frag, const float* __restrict__ bproj,
    const float* __restrict__ gamma, float* __restrict__ out) {
    extern __shared__ char sm[];
    unsigned short* lds_list = (unsigned short*)(sm + AP2_LIST);
    const int tid  = threadIdx.x;
    const int lane = tid & 63;
    const int h    = tid >> 6;
    const int l15  = lane & 15;
    const int l4   = lane >> 4;
    const int p0   = blockIdx.x * 32;

    // stage all 32 points' slot lists: 1 KB, one coalesced pass
    if (tid < 256)
        ((unsigned int*)lds_list)[tid] = ((const unsigned int*)(list + (size_t)p0 * CAP_))[tid];
    __syncthreads();

    // Phase A: 12 threads per point, 32 channels each
    {
        int p = tid / 12, part = tid % 12;
        int bn = p0 + p;
        int b  = bn >> 13;
        int c  = fillcnt[bn];
        int cc = c < CAP_ ? c : CAP_;
        f32x4 s[8];
        #pragma unroll
        for (int u = 0; u < 8; ++u) s[u] = (f32x4){0.f, 0.f, 0.f, 0.f};
        int e = 0;
        for (; e + 1 < cc; e += 2) {
            int sl0 = lds_list[p * CAP_ + e];
            int sl1 = lds_list[p * CAP_ + e + 1];
            const unsigned char* r0 = slotbuf + ((size_t)(b << 14) + sl0) * C_ + part * 32;
            const unsigned char* r1 = slotbuf + ((size_t)(b << 14) + sl1) * C_ + part * 32;
            u32x4 a0 = __builtin_nontemporal_load((const u32x4*)r0);
            u32x4 a1 = __builtin_nontemporal_load((const u32x4*)(r0 + 16));
            u32x4 b0 = __builtin_nontemporal_load((const u32x4*)r1);
            u32x4 b1 = __builtin_nontemporal_load((const u32x4*)(r1 + 16));
            #pragma unroll
            for (int q = 0; q < 4; ++q) {
                s[q][0] += __builtin_amdgcn_cvt_f32_fp8((int)a0[q], 0) + __builtin_amdgcn_cvt_f32_fp8((int)b0[q], 0);
                s[q][1] += __builtin_amdgcn_cvt_f32_fp8((int)a0[q], 1) + __builtin_amdgcn_cvt_f32_fp8((int)b0[q], 1);
                s[q][2] += __builtin_amdgcn_cvt_f32_fp8((int)a0[q], 2) + __builtin_amdgcn_cvt_f32_fp8((int)b0[q], 2);
                s[q][3] += __builtin_amdgcn_cvt_f32_fp8((int)a0[q], 3) + __builtin_amdgcn_cvt_f32_fp8((int)b0[q], 3);
                s[4 + q][0] += __builtin_amdgcn_cvt_f32_fp8((int)a1[q], 0) + __builtin_amdgcn_cvt_f32_fp8((int)b1[q], 0);
                s[4 + q][1] += __builtin_amdgcn_cvt_f32_fp8((int)a1[q], 1) + __builtin_amdgcn_cvt_f32_fp8((int)b1[q], 1);
                s[4 + q][2] += __builtin_amdgcn_cvt_f32_fp8((int)a1[q], 2) + __builtin_amdgcn_cvt_f32_fp8((int)b1[q], 2);
                s[4 + q][3] += __builtin_amdgcn_cvt_f32_fp8((int)a1[q], 3) + __builtin_amdgcn_cvt_f32_fp8((int)b1[q], 3);
            }
        }
        if (e < cc) {
            int sl = lds_list[p * CAP_ + e];
            const unsigned char* row = slotbuf + ((size_t)(b << 14) + sl) * C_ + part * 32;
            u32x4 w0 = __builtin_nontemporal_load((const u32x4*)row);
            u32x4 w1 = __builtin_nontemporal_load((const u32x4*)(row + 16));
            #pragma unroll
            for (int q = 0; q < 4; ++q) {
                s[q][0] += __builtin_amdgcn_cvt_f32_fp8((int)w0[q], 0);
                s[q][1] += __builtin_amdgcn_cvt_f32_fp8((int)w0[q], 1);
                s[q][2] += __builtin_amdgcn_cvt_f32_fp8((int)w0[q], 2);
                s[q][3] += __builtin_amdgcn_cvt_f32_fp8((int)w0[q], 3);
                s[4 + q][0] += __builtin_amdgcn_cvt_f32_fp8((int)w1[q], 0);
                s[4 + q][1] += __builtin_amdgcn_cvt_f32_fp8((int)w1[q], 1);
                s[4 + q][2] += __builtin_amdgcn_cvt_f32_fp8((int)w1[q], 2);
                s[4 + q][3] += __builtin_amdgcn_cvt_f32_fp8((int)w1[q], 3);
            }
        }
        float inv = 1.f / (float)(c < 1 ? 1 : c);
        #pragma unroll
        for (int u = 0; u < 8; ++u) {
            bvec4 w = { f2bf(s[u][0] * inv), f2bf(s[u][1] * inv),
                        f2bf(s[u][2] * inv), f2bf(s[u][3] * inv) };
            *(bvec4*)(sm + swzA(p, (part * 32 + u * 4) * 2)) = w;
        }
    }
    __syncthreads();

    // Phase B: proj GEMM (swapped operands), M=32 points
    f32x4 acc[4][2];
    #pragma unroll
    for (int mt = 0; mt < 4; ++mt)
        #pragma unroll
        for (int nt = 0; nt < 2; ++nt) acc[mt][nt] = (f32x4){0.f, 0.f, 0.f, 0.f};
    const short* wb = wp_frag + (size_t)(h * 48) * 512;
    #pragma unroll
    for (int kk = 0; kk < 12; ++kk) {
        bvec8 xb[2];
        #pragma unroll
        for (int nt = 0; nt < 2; ++nt)
            xb[nt] = *(const bvec8*)(sm + swzA(nt * 16 + l15, kk * 64 + l4 * 16));
        #pragma unroll
        for (int mt = 0; mt < 4; ++mt) {
            bvec8 wf = *(const bvec8*)(wb + (size_t)((kk * 4 + mt) * 64 + lane) * 8);
            #pragma unroll
            for (int nt = 0; nt < 2; ++nt)
                acc[mt][nt] = __builtin_amdgcn_mfma_f32_16x16x32_bf16(wf, xb[nt], acc[mt][nt], 0, 0, 0);
        }
    }
    #pragma unroll
    for (int mt = 0; mt < 4; ++mt)
        #pragma unroll
        for (int nt = 0; nt < 2; ++nt) {
            int pt   = p0 + nt * 16 + l15;
            int col0 = h * DH_ + mt * 16 + l4 * 4;
            f32x4 fv = *(const f32x4*)(feats + (size_t)pt * C_ + col0);
            f32x4 gv = *(const f32x4*)(gamma + col0);
            f32x4 bv = *(const f32x4*)(bproj + col0);
            float has = fillcnt[pt] > 0 ? 1.f : 0.f;
            f32x4 r;
            #pragma unroll
            for (int j = 0; j < 4; ++j)
                r[j] = fv[j] + (acc[mt][nt][j] + bv[j]) * gv[j] * has;
            *(f32x4*)(out + (size_t)pt * C_ + col0) = r;
        }
}

// ---- MODE B final (fallback): avg from atomic acc (= out, in place) + proj.
#define AP_LDS (64 * 768)
__global__ __launch_bounds__(384, 4) void avgproj_kernel(
    const float* __restrict__ feats, const int* __restrict__ fillcnt,
    const short* __restrict__ wp_frag, const float* __restrict__ bproj,
    const float* __restrict__ gamma, float* out) {
    extern __shared__ char sm[];
    const int tid  = threadIdx.x;
    const int lane = tid & 63;
    const int h    = tid >> 6;
    const int l15  = lane & 15;
    const int l4   = lane >> 4;
    const int p0   = blockIdx.x * 64;

    {
        int p = tid / 6, part = tid - p * 6;
        int cv = fillcnt[p0 + p];
        float inv = 1.f / (float)(cv < 1 ? 1 : cv);
        const float* src = out + (size_t)(p0 + p) * C_ + part * 64;
        #pragma unroll
        for (int u = 0; u < 16; ++u) {
            f32x4 a = *(const f32x4*)(src + u * 4);
            bvec4 w = { f2bf(a[0] * inv), f2bf(a[1] * inv), f2bf(a[2] * inv), f2bf(a[3] * inv) };
            *(bvec4*)(sm + swzA(p, (part * 64 + u * 4) * 2)) = w;
        }
    }
    __syncthreads();

    f32x4 acc[4][4];
    #pragma unroll
    for (int mt = 0; mt < 4; ++mt)
        #pragma unroll
        for (int nt = 0; nt < 4; ++nt) acc[mt][nt] = (f32x4){0.f, 0.f, 0.f, 0.f};
    const short* wb = wp_frag + (size_t)(h * 48) * 512;
    #pragma unroll
    for (int kk = 0; kk < 12; ++kk) {
        bvec8 xb[4];
        #pragma unroll
        for (int nt = 0; nt < 4; ++nt)
            xb[nt] = *(const bvec8*)(sm + swzA(nt * 16 + l15, kk * 64 + l4 * 16));
        #pragma unroll
        for (int mt = 0; mt < 4; ++mt) {
            bvec8 wf = *(const bvec8*)(wb + (size_t)((kk * 4 + mt) * 64 + lane) * 8);
            #pragma unroll
            for (int nt = 0; nt < 4; ++nt)
                acc[mt][nt] = __builtin_amdgcn_mfma_f32_16x16x32_bf16(wf, xb[nt], acc[mt][nt], 0, 0, 0);
        }
    }
    #pragma unroll
    for (int mt = 0; mt < 4; ++mt)
        #pragma unroll
        for (int nt = 0; nt < 4; ++nt) {
            int pt   = p0 + nt * 16 + l15;
            int col0 = h * DH_ + mt * 16 + l4 * 4;
            f32x4 fv = *(const f32x4*)(feats + (size_t)pt * C_ + col0);
            f32x4 gv = *(const f32x4*)(gamma + col0);
            f32x4 bv = *(const f32x4*)(bproj + col0);
            float has = fillcnt[pt] > 0 ? 1.f : 0.f;
            f32x4 r;
            #pragma unroll
            for (int j = 0; j < 4; ++j)
                r[j] = fv[j] + (acc[mt][nt][j] + bv[j]) * gv[j] * has;
            *(f32x4*)(out + (size_t)pt * C_ + col0) = r;
        }
}

extern "C" void kernel_launch(void* const* d_in, const int* in_sizes, int n_in,
                              void* d_out, int out_size, void* d_ws, size_t ws_size,
                              hipStream_t stream) {
    const float* feats = (const float*)d_in[0];
    const int*   gidx  = (const int*)d_in[1];
    const float* gmask = (const float*)d_in[2];
    const float* wqkv  = (const float*)d_in[3];
    const float* wproj = (const float*)d_in[4];
    const float* bproj = (const float*)d_in[5];
    const float* gamma = (const float*)d_in[6];
    float* out = (float*)d_out;

    char* ws = (char*)d_ws;
    short* wq_frag = (short*)ws;                               // 884736
    short* wp_frag = (short*)(ws + 884736);                    // 294912
    int*   fillcnt = (int*)(ws + 1179648);                     // 262144
    // MODE A layout:
    unsigned short* list = (unsigned short*)(ws + 1441792);    // 2 MiB (CAP 16)
    unsigned char* slotA = (unsigned char*)(ws + 3538944);     // 50331648
    unsigned char* qbA   = (unsigned char*)(ws + 53870592);    // 25165824
    unsigned char* kbA   = (unsigned char*)(ws + 79036416);    // 25165824
    unsigned char* vbA   = (unsigned char*)(ws + 104202240);   // 25165824 -> 129368064 total
    const size_t neededA = 129368064;
    // MODE B layout:
    unsigned char* qbB = (unsigned char*)(ws + 1441792);
    unsigned char* kbB = (unsigned char*)(ws + 26607616);
    unsigned char* vbB = (unsigned char*)(ws + 51773440);

    convw_kernel<<<(55296 + 18432 + 255) / 256, 256, 0, stream>>>(wqkv, wproj, wq_frag, wp_frag);
    (void)hipMemsetAsync(fillcnt, 0, (size_t)B_ * NMAX * sizeof(int), stream);
    fill_kernel<<<(B_ * G_ * K_ + 255) / 256, 256, 0, stream>>>(gidx, gmask, fillcnt, list);

    if (ws_size >= neededA) {
        qkv_kernel<<<(B_ * NMAX) / QKV_M, 768, QKV_LDS, stream>>>(feats, wq_frag, qbA, kbA, vbA);
        attn2_kernel<true><<<B_ * G_, 384, ATTN_LDS, stream>>>(gidx, gmask, qbA, kbA, vbA,
                                                               slotA, nullptr);
        avgproj2_kernel<<<(B_ * NMAX) / 32, 384, AP2_LDS, stream>>>(feats, fillcnt, list, slotA,
                                                                    wp_frag, bproj, gamma, out);
    } else {
        (void)hipMemsetAsync(out, 0, (size_t)B_ * NMAX * C_ * sizeof(float), stream);
        qkv_kernel<<<(B_ * NMAX) / QKV_M, 768, QKV_LDS, stream>>>(feats, wq_frag, qbB, kbB, vbB);
        attn2_kernel<false><<<B_ * G_, 384, ATTN_LDS, stream>>>(gidx, gmask, qbB, kbB, vbB,
                                                                nullptr, out);
        avgproj_kernel<<<(B_ * NMAX) / 64, 384, AP_LDS, stream>>>(feats, fillcnt, wp_frag,
                                                                  bproj, gamma, out);
    }
}

// Round 17
// 185.748 us; speedup vs baseline: 1.5358x; 1.5358x over previous
//
#include <hip/hip_runtime.h>
#include <hip/hip_bf16.h>

#define B_   8
#define NMAX 8192
#define C_   384
#define G_   512
#define K_   32
#define H_   6
#define DH_  64
#define CAP_ 16

typedef short bvec8 __attribute__((ext_vector_type(8)));
typedef short bvec4 __attribute__((ext_vector_type(4)));
typedef _Float16 hvec4 __attribute__((ext_vector_type(4)));
typedef float f32x4 __attribute__((ext_vector_type(4)));
typedef unsigned int u32x4 __attribute__((ext_vector_type(4)));

__device__ __forceinline__ short f2bf(float f) {
    union { __hip_bfloat16 b; short s; } u;
    u.b = __float2bfloat16(f);
    return u.s;
}

// XOR-swizzled [rows][768 B] bf16 tile (proven): colb in bytes
__device__ __forceinline__ int swzA(int row, int colb) { return row * 768 + (colb ^ ((row & 7) << 4)); }
// XOR-swizzled [rows][384 B] fp8 tile (stage buffers)
__device__ __forceinline__ int swzS(int row, int colb) { return row * 384 + (colb ^ ((row & 7) << 4)); }

// Fragment-major weight packing (proven R6/R7)
__global__ void convw_kernel(const float* __restrict__ wqkv, const float* __restrict__ wproj,
                             short* __restrict__ wq_frag, short* __restrict__ wp_frag) {
    int i = blockIdx.x * 256 + threadIdx.x;
    if (i < 55296) {
        int lane = i & 63, t = i >> 6;
        int nt = t & 3, kk = (t >> 2) % 12, hh = (t >> 2) / 12;
        int row  = hh * 64 + nt * 16 + (lane & 15);
        int col0 = kk * 32 + (lane >> 4) * 8;
        const float* src = wqkv + (size_t)row * C_ + col0;
        bvec8 v;
        #pragma unroll
        for (int e = 0; e < 8; ++e) v[e] = f2bf(src[e]);
        *(bvec8*)(wq_frag + (size_t)i * 8) = v;
    } else if (i < 55296 + 18432) {
        int j = i - 55296;
        int lane = j & 63, t = j >> 6;
        int nt = t & 3, kk = (t >> 2) % 12, h = (t >> 2) / 12;
        int row  = h * 64 + nt * 16 + (lane & 15);
        int col0 = kk * 32 + (lane >> 4) * 8;
        const float* src = wproj + (size_t)row * C_ + col0;
        bvec8 v;
        #pragma unroll
        for (int e = 0; e < 8; ++e) v[e] = f2bf(src[e]);
        *(bvec8*)(wp_frag + (size_t)j * 8) = v;
    }
}

// Inverted index: per point, list of valid slot-ids (within batch). fillcnt == cnt.
__global__ void fill_kernel(const int* __restrict__ gidx, const float* __restrict__ gmask,
                            int* __restrict__ fillcnt, unsigned short* __restrict__ list) {
    int t = blockIdx.x * 256 + threadIdx.x;
    if (t >= B_ * G_ * K_) return;
    float m = gmask[t];
    if (m <= 0.f) return;
    int v = gidx[t];
    v = v < 0 ? 0 : v;
    int b = t >> 14;
    int bn = b * NMAX + v;
    int pos = atomicAdd(&fillcnt[bn], 1);
    if (pos < CAP_) list[(size_t)bn * CAP_ + pos] = (unsigned short)(t - (b << 14));
}

// ---- Dense QKV: q/k/v fp8 = feats @ W^T, swapped-operand MFMA.
// R17 = R15 (empirical optimum: 93us, FETCH 56MB, no spills):
// QKV_M=128, 768 threads = 12 waves, wave = (head, dh-half), 1 block/CU.
// Ledger: R13 M-half split (-), R14 2-block/CU (-, L2 thrash), R16 3-mat
// fusion (-, acc spill: VGPR 84 < 96 needed, WRITE 310MB). Do not perturb.
#define QKV_M     128
#define QKV_STAGE (QKV_M * 768)                    // 98304
#define QKV_LDS   (QKV_M * 768 + QKV_M * 384)      // 147456
__global__ __launch_bounds__(768, 3) void qkv_kernel(
    const float* __restrict__ feats, const short* __restrict__ wq_frag,
    unsigned char* __restrict__ qb, unsigned char* __restrict__ kb,
    unsigned char* __restrict__ vb) {
    extern __shared__ char sm[];
    char* stage = sm + QKV_STAGE;
    const int tid  = threadIdx.x;
    const int lane = tid & 63;
    const int h2   = tid >> 6;          // wave id 0..11: head = h2>>1, dh-half = h2&1
    const int h    = h2 >> 1;
    const int mh   = h2 & 1;
    const int l15  = lane & 15;
    const int l4   = lane >> 4;
    const int pt0  = blockIdx.x * QKV_M;

    #pragma unroll
    for (int i = 0; i < 16; ++i) {
        int p = i * 768 + tid;             // 12288 f32x4 tasks
        int row = p / 96, seg = p % 96;
        f32x4 f = *(const f32x4*)(feats + (size_t)(pt0 + row) * C_ + seg * 4);
        bvec4 v4 = { f2bf(f[0]), f2bf(f[1]), f2bf(f[2]), f2bf(f[3]) };
        *(bvec4*)(sm + swzA(row, seg * 8)) = v4;
    }
    __syncthreads();

    for (int mat = 0; mat < 3; ++mat) {
        const short* wb = wq_frag + (size_t)((mat * 6 + h) * 48) * 512;
        unsigned char* dst = (mat == 0) ? qb : (mat == 1) ? kb : vb;
        f32x4 acc[2][8];
        #pragma unroll
        for (int mt = 0; mt < 2; ++mt)
            #pragma unroll
            for (int nt = 0; nt < 8; ++nt) acc[mt][nt] = (f32x4){0.f, 0.f, 0.f, 0.f};
        #pragma unroll
        for (int kk = 0; kk < 12; ++kk) {
            bvec8 xb[8];
            #pragma unroll
            for (int nt = 0; nt < 8; ++nt)
                xb[nt] = *(const bvec8*)(sm + swzA(nt * 16 + l15, kk * 64 + l4 * 16));
            #pragma unroll
            for (int mt = 0; mt < 2; ++mt) {
                bvec8 wf = *(const bvec8*)(wb + (size_t)((kk * 4 + mh * 2 + mt) * 64 + lane) * 8);
                #pragma unroll
                for (int nt = 0; nt < 8; ++nt)
                    acc[mt][nt] = __builtin_amdgcn_mfma_f32_16x16x32_bf16(wf, xb[nt], acc[mt][nt], 0, 0, 0);
            }
        }
        // D row = dh = mh*32 + mt*16 + l4*4 + j ; col = tok = nt*16 + l15
        #pragma unroll
        for (int mt = 0; mt < 2; ++mt)
            #pragma unroll
            for (int nt = 0; nt < 8; ++nt) {
                int w = __builtin_amdgcn_cvt_pk_fp8_f32(acc[mt][nt][0], acc[mt][nt][1], 0, false);
                w = __builtin_amdgcn_cvt_pk_fp8_f32(acc[mt][nt][2], acc[mt][nt][3], w, true);
                *(unsigned int*)(stage + swzS(nt * 16 + l15, h * DH_ + mh * 32 + mt * 16 + l4 * 4))
                    = (unsigned int)w;
            }
        __syncthreads();
        // coalesced full-row copy: 3072 chunks of 16 B (row = 384 B = 6 full lines)
        #pragma unroll
        for (int it = 0; it < 4; ++it) {
            int chunk = it * 768 + tid;
            int row = chunk / 24, off = chunk % 24;
            u32x4 v = *(const u32x4*)(stage + swzS(row, off * 16));
            *(u32x4*)(dst + (size_t)(pt0 + row) * C_ + off * 16) = v;
        }
        __syncthreads();   // stage reused by next mat
    }
}

// ---- Per-group attention. SLOT=true: write PV rows (fp8) to slotbuf, NO atomics.
#define AQ_OFF   0              // 6 x [32][72] fp8 q ; also PV stage [32][384] fp8 (12288 B)
#define AK_OFF   13824          // 6 x [32][72]
#define AV_OFF   27648          // 6 x [32][68]
#define AMASK    40704
#define AIDX     40832
#define ATTN_LDS 40960

template<bool SLOT>
__global__ __launch_bounds__(384, 5) void attn2_kernel(
    const int* __restrict__ gidx, const float* __restrict__ gmask,
    const unsigned char* __restrict__ qb, const unsigned char* __restrict__ kb,
    const unsigned char* __restrict__ vb,
    unsigned char* __restrict__ slotbuf, float* __restrict__ acc_out) {
    extern __shared__ char sm[];
    float* mask_lds = (float*)(sm + AMASK);
    int*   idx_lds  = (int*)(sm + AIDX);

    const int tid  = threadIdx.x;
    const int lane = tid & 63;
    const int h    = tid >> 6;
    const int bg   = blockIdx.x;
    const int b    = bg >> 9;
    const int l15  = lane & 15;
    const int l4   = lane >> 4;

    if (tid < 32) {
        int v = gidx[(size_t)bg * K_ + tid];
        v = v < 0 ? 0 : v;
        idx_lds[tid]  = v;
        mask_lds[tid] = gmask[(size_t)bg * K_ + tid];
    }
    __syncthreads();

    char* qh = sm + AQ_OFF + h * 2304;
    char* kh = sm + AK_OFF + h * 2304;
    char* vh = sm + AV_OFF + h * 2176;

    const int t8 = lane >> 3, c8 = lane & 7;
    #pragma unroll
    for (int i = 0; i < 4; ++i) {
        int t = i * 8 + t8;
        size_t base = (size_t)(b * NMAX + idx_lds[t]) * C_ + h * DH_;
        long qv = *(const long*)(qb + base + c8 * 8);
        long kv = *(const long*)(kb + base + c8 * 8);
        long vv = *(const long*)(vb + base + c8 * 8);
        *(long*)(qh + t * 72 + c8 * 8) = qv;
        *(long*)(kh + t * 72 + c8 * 8) = kv;
        *(int*)(vh + t * 68 + c8 * 8)     = (int)(vv & 0xffffffffL);
        *(int*)(vh + t * 68 + c8 * 8 + 4) = (int)(((unsigned long)vv) >> 32);
    }

    // scores^T = k @ q^T (fp8)
    f32x4 sc[2][2];
    #pragma unroll
    for (int mt = 0; mt < 2; ++mt)
        #pragma unroll
        for (int nt = 0; nt < 2; ++nt) sc[mt][nt] = (f32x4){0.f, 0.f, 0.f, 0.f};
    #pragma unroll
    for (int kk = 0; kk < 2; ++kk) {
        long ka0 = *(const long*)(kh + l15 * 72 + kk * 32 + l4 * 8);
        long ka1 = *(const long*)(kh + (16 + l15) * 72 + kk * 32 + l4 * 8);
        long qa0 = *(const long*)(qh + l15 * 72 + kk * 32 + l4 * 8);
        long qa1 = *(const long*)(qh + (16 + l15) * 72 + kk * 32 + l4 * 8);
        sc[0][0] = __builtin_amdgcn_mfma_f32_16x16x32_fp8_fp8(ka0, qa0, sc[0][0], 0, 0, 0);
        sc[0][1] = __builtin_amdgcn_mfma_f32_16x16x32_fp8_fp8(ka0, qa1, sc[0][1], 0, 0, 0);
        sc[1][0] = __builtin_amdgcn_mfma_f32_16x16x32_fp8_fp8(ka1, qa0, sc[1][0], 0, 0, 0);
        sc[1][1] = __builtin_amdgcn_mfma_f32_16x16x32_fp8_fp8(ka1, qa1, sc[1][1], 0, 0, 0);
    }

    // softmax over keys (proven)
    float bk[2][4];
    #pragma unroll
    for (int mt = 0; mt < 2; ++mt)
        #pragma unroll
        for (int j = 0; j < 4; ++j)
            bk[mt][j] = mask_lds[mt * 16 + l4 * 4 + j] > 0.f ? 0.f : -1e30f;

    hvec4 pfrag[2][2];
    #pragma unroll
    for (int nt = 0; nt < 2; ++nt) {
        float s[2][4];
        float mx = -1e30f;
        #pragma unroll
        for (int mt = 0; mt < 2; ++mt)
            #pragma unroll
            for (int j = 0; j < 4; ++j) {
                s[mt][j] = sc[mt][nt][j] * 0.125f + bk[mt][j];
                mx = fmaxf(mx, s[mt][j]);
            }
        mx = fmaxf(mx, __shfl_xor(mx, 16));
        mx = fmaxf(mx, __shfl_xor(mx, 32));
        float sum = 0.f;
        #pragma unroll
        for (int mt = 0; mt < 2; ++mt)
            #pragma unroll
            for (int j = 0; j < 4; ++j) {
                s[mt][j] = __expf(s[mt][j] - mx);
                sum += s[mt][j];
            }
        sum += __shfl_xor(sum, 16);
        sum += __shfl_xor(sum, 32);
        float inv = 1.f / sum;
        #pragma unroll
        for (int mt = 0; mt < 2; ++mt)
            pfrag[mt][nt] = (hvec4){ (_Float16)(s[mt][0] * inv), (_Float16)(s[mt][1] * inv),
                                     (_Float16)(s[mt][2] * inv), (_Float16)(s[mt][3] * inv) };
    }

    // vfrag from LDS (fp8 -> f16)
    hvec4 vfrag[2][4];
    #pragma unroll
    for (int c = 0; c < 2; ++c)
        #pragma unroll
        for (int dt = 0; dt < 4; ++dt) {
            hvec4 vv;
            #pragma unroll
            for (int e = 0; e < 4; ++e) {
                int byt = *(const unsigned char*)(vh + (c * 16 + l4 * 4 + e) * 68 + dt * 16 + l15);
                vv[e] = (_Float16)__builtin_amdgcn_cvt_f32_fp8(byt, 0);
            }
            vfrag[c][dt] = vv;
        }

    // PV: out^T[dh][q]
    f32x4 po[4][2];
    #pragma unroll
    for (int dt = 0; dt < 4; ++dt)
        #pragma unroll
        for (int qt = 0; qt < 2; ++qt) po[dt][qt] = (f32x4){0.f, 0.f, 0.f, 0.f};
    #pragma unroll
    for (int c = 0; c < 2; ++c)
        #pragma unroll
        for (int dt = 0; dt < 4; ++dt)
            #pragma unroll
            for (int qt = 0; qt < 2; ++qt)
                po[dt][qt] = __builtin_amdgcn_mfma_f32_16x16x16f16(vfrag[c][dt], pfrag[c][qt], po[dt][qt], 0, 0, 0);

    if constexpr (SLOT) {
        // stage PV^T -> [tok][384] fp8 in the (dead) q region, then coalesced row copy
        __syncthreads();          // all waves done with their q/k LDS reads
        char* stage = sm + AQ_OFF;
        #pragma unroll
        for (int dt = 0; dt < 4; ++dt)
            #pragma unroll
            for (int qt = 0; qt < 2; ++qt) {
                int w = __builtin_amdgcn_cvt_pk_fp8_f32(po[dt][qt][0], po[dt][qt][1], 0, false);
                w = __builtin_amdgcn_cvt_pk_fp8_f32(po[dt][qt][2], po[dt][qt][3], w, true);
                *(unsigned int*)(stage + swzS(qt * 16 + l15, h * DH_ + dt * 16 + l4 * 4))
                    = (unsigned int)w;
            }
        __syncthreads();
        #pragma unroll
        for (int it = 0; it < 2; ++it) {
            int chunk = it * 384 + tid;        // 768 chunks of 16 B
            int row = chunk / 24, off = chunk % 24;
            u32x4 v = *(const u32x4*)(stage + swzS(row, off * 16));
            *(u32x4*)(slotbuf + ((size_t)bg * K_ + row) * C_ + off * 16) = v;
        }
    } else {
        #pragma unroll
        for (int qt = 0; qt < 2; ++qt) {
            int tok = qt * 16 + l15;
            float mk = mask_lds[tok];
            size_t rowb = (size_t)(b * NMAX + idx_lds[tok]) * C_ + h * DH_ + l4 * 4;
            #pragma unroll
            for (int dt = 0; dt < 4; ++dt)
                #pragma unroll
                for (int j = 0; j < 4; ++j)
                    if (mk > 0.f) atomicAdd(acc_out + rowb + dt * 16 + j, po[dt][qt][j]);
        }
    }
}

// ---- MODE A final: gather slot rows -> avg -> proj -> out. 32 points/block.
// Slot-lists staged in LDS, NT slot reads, x2 unroll (proven R13).
#define AP2_LIST (32 * 768)
#define AP2_LDS  (32 * 768 + 1024)
__global__ __launch_bounds__(384, 5) void avgproj2_kernel(
    const float* __restrict__ feats, const int* __restrict__ fillcnt,
    const unsigned short* __restrict__ list, const unsigned char* __restrict__ slotbuf,
    const short* __restrict__ wp_frag, const float* __restrict__ bproj,
    const float* __restrict__ gamma, float* __restrict__ out) {
    extern __shared__ char sm[];
    unsigned short* lds_list = (unsigned short*)(sm + AP2_LIST);
    const int tid  = threadIdx.x;
    const int lane = tid & 63;
    const int h    = tid >> 6;
    const int l15  = lane & 15;
    const int l4   = lane >> 4;
    const int p0   = blockIdx.x * 32;

    // stage all 32 points' slot lists: 1 KB, one coalesced pass
    if (tid < 256)
        ((unsigned int*)lds_list)[tid] = ((const unsigned int*)(list + (size_t)p0 * CAP_))[tid];
    __syncthreads();

    // Phase A: 12 threads per point, 32 channels each
    {
        int p = tid / 12, part = tid % 12;
        int bn = p0 + p;
        int b  = bn >> 13;
        int c  = fillcnt[bn];
        int cc = c < CAP_ ? c : CAP_;
        f32x4 s[8];
        #pragma unroll
        for (int u = 0; u < 8; ++u) s[u] = (f32x4){0.f, 0.f, 0.f, 0.f};
        int e = 0;
        for (; e + 1 < cc; e += 2) {
            int sl0 = lds_list[p * CAP_ + e];
            int sl1 = lds_list[p * CAP_ + e + 1];
            const unsigned char* r0 = slotbuf + ((size_t)(b << 14) + sl0) * C_ + part * 32;
            const unsigned char* r1 = slotbuf + ((size_t)(b << 14) + sl1) * C_ + part * 32;
            u32x4 a0 = __builtin_nontemporal_load((const u32x4*)r0);
            u32x4 a1 = __builtin_nontemporal_load((const u32x4*)(r0 + 16));
            u32x4 b0 = __builtin_nontemporal_load((const u32x4*)r1);
            u32x4 b1 = __builtin_nontemporal_load((const u32x4*)(r1 + 16));
            #pragma unroll
            for (int q = 0; q < 4; ++q) {
                s[q][0] += __builtin_amdgcn_cvt_f32_fp8((int)a0[q], 0) + __builtin_amdgcn_cvt_f32_fp8((int)b0[q], 0);
                s[q][1] += __builtin_amdgcn_cvt_f32_fp8((int)a0[q], 1) + __builtin_amdgcn_cvt_f32_fp8((int)b0[q], 1);
                s[q][2] += __builtin_amdgcn_cvt_f32_fp8((int)a0[q], 2) + __builtin_amdgcn_cvt_f32_fp8((int)b0[q], 2);
                s[q][3] += __builtin_amdgcn_cvt_f32_fp8((int)a0[q], 3) + __builtin_amdgcn_cvt_f32_fp8((int)b0[q], 3);
                s[4 + q][0] += __builtin_amdgcn_cvt_f32_fp8((int)a1[q], 0) + __builtin_amdgcn_cvt_f32_fp8((int)b1[q], 0);
                s[4 + q][1] += __builtin_amdgcn_cvt_f32_fp8((int)a1[q], 1) + __builtin_amdgcn_cvt_f32_fp8((int)b1[q], 1);
                s[4 + q][2] += __builtin_amdgcn_cvt_f32_fp8((int)a1[q], 2) + __builtin_amdgcn_cvt_f32_fp8((int)b1[q], 2);
                s[4 + q][3] += __builtin_amdgcn_cvt_f32_fp8((int)a1[q], 3) + __builtin_amdgcn_cvt_f32_fp8((int)b1[q], 3);
            }
        }
        if (e < cc) {
            int sl = lds_list[p * CAP_ + e];
            const unsigned char* row = slotbuf + ((size_t)(b << 14) + sl) * C_ + part * 32;
            u32x4 w0 = __builtin_nontemporal_load((const u32x4*)row);
            u32x4 w1 = __builtin_nontemporal_load((const u32x4*)(row + 16));
            #pragma unroll
            for (int q = 0; q < 4; ++q) {
                s[q][0] += __builtin_amdgcn_cvt_f32_fp8((int)w0[q], 0);
                s[q][1] += __builtin_amdgcn_cvt_f32_fp8((int)w0[q], 1);
                s[q][2] += __builtin_amdgcn_cvt_f32_fp8((int)w0[q], 2);
                s[q][3] += __builtin_amdgcn_cvt_f32_fp8((int)w0[q], 3);
                s[4 + q][0] += __builtin_amdgcn_cvt_f32_fp8((int)w1[q], 0);
                s[4 + q][1] += __builtin_amdgcn_cvt_f32_fp8((int)w1[q], 1);
                s[4 + q][2] += __builtin_amdgcn_cvt_f32_fp8((int)w1[q], 2);
                s[4 + q][3] += __builtin_amdgcn_cvt_f32_fp8((int)w1[q], 3);
            }
        }
        float inv = 1.f / (float)(c < 1 ? 1 : c);
        #pragma unroll
        for (int u = 0; u < 8; ++u) {
            bvec4 w = { f2bf(s[u][0] * inv), f2bf(s[u][1] * inv),
                        f2bf(s[u][2] * inv), f2bf(s[u][3] * inv) };
            *(bvec4*)(sm + swzA(p, (part * 32 + u * 4) * 2)) = w;
        }
    }
    __syncthreads();

    // Phase B: proj GEMM (swapped operands), M=32 points
    f32x4 acc[4][2];
    #pragma unroll
    for (int mt = 0; mt < 4; ++mt)
        #pragma unroll
        for (int nt = 0; nt < 2; ++nt) acc[mt][nt] = (f32x4){0.f, 0.f, 0.f, 0.f};
    const short* wb = wp_frag + (size_t)(h * 48) * 512;
    #pragma unroll
    for (int kk = 0; kk < 12; ++kk) {
        bvec8 xb[2];
        #pragma unroll
        for (int nt = 0; nt < 2; ++nt)
            xb[nt] = *(const bvec8*)(sm + swzA(nt * 16 + l15, kk * 64 + l4 * 16));
        #pragma unroll
        for (int mt = 0; mt < 4; ++mt) {
            bvec8 wf = *(const bvec8*)(wb + (size_t)((kk * 4 + mt) * 64 + lane) * 8);
            #pragma unroll
            for (int nt = 0; nt < 2; ++nt)
                acc[mt][nt] = __builtin_amdgcn_mfma_f32_16x16x32_bf16(wf, xb[nt], acc[mt][nt], 0, 0, 0);
        }
    }
    #pragma unroll
    for (int mt = 0; mt < 4; ++mt)
        #pragma unroll
        for (int nt = 0; nt < 2; ++nt) {
            int pt   = p0 + nt * 16 + l15;
            int col0 = h * DH_ + mt * 16 + l4 * 4;
            f32x4 fv = *(const f32x4*)(feats + (size_t)pt * C_ + col0);
            f32x4 gv = *(const f32x4*)(gamma + col0);
            f32x4 bv = *(const f32x4*)(bproj + col0);
            float has = fillcnt[pt] > 0 ? 1.f : 0.f;
            f32x4 r;
            #pragma unroll
            for (int j = 0; j < 4; ++j)
                r[j] = fv[j] + (acc[mt][nt][j] + bv[j]) * gv[j] * has;
            *(f32x4*)(out + (size_t)pt * C_ + col0) = r;
        }
}

// ---- MODE B final (fallback): avg from atomic acc (= out, in place) + proj.
#define AP_LDS (64 * 768)
__global__ __launch_bounds__(384, 4) void avgproj_kernel(
    const float* __restrict__ feats, const int* __restrict__ fillcnt,
    const short* __restrict__ wp_frag, const float* __restrict__ bproj,
    const float* __restrict__ gamma, float* out) {
    extern __shared__ char sm[];
    const int tid  = threadIdx.x;
    const int lane = tid & 63;
    const int h    = tid >> 6;
    const int l15  = lane & 15;
    const int l4   = lane >> 4;
    const int p0   = blockIdx.x * 64;

    {
        int p = tid / 6, part = tid - p * 6;
        int cv = fillcnt[p0 + p];
        float inv = 1.f / (float)(cv < 1 ? 1 : cv);
        const float* src = out + (size_t)(p0 + p) * C_ + part * 64;
        #pragma unroll
        for (int u = 0; u < 16; ++u) {
            f32x4 a = *(const f32x4*)(src + u * 4);
            bvec4 w = { f2bf(a[0] * inv), f2bf(a[1] * inv), f2bf(a[2] * inv), f2bf(a[3] * inv) };
            *(bvec4*)(sm + swzA(p, (part * 64 + u * 4) * 2)) = w;
        }
    }
    __syncthreads();

    f32x4 acc[4][4];
    #pragma unroll
    for (int mt = 0; mt < 4; ++mt)
        #pragma unroll
        for (int nt = 0; nt < 4; ++nt) acc[mt][nt] = (f32x4){0.f, 0.f, 0.f, 0.f};
    const short* wb = wp_frag + (size_t)(h * 48) * 512;
    #pragma unroll
    for (int kk = 0; kk < 12; ++kk) {
        bvec8 xb[4];
        #pragma unroll
        for (int nt = 0; nt < 4; ++nt)
            xb[nt] = *(const bvec8*)(sm + swzA(nt * 16 + l15, kk * 64 + l4 * 16));
        #pragma unroll
        for (int mt = 0; mt < 4; ++mt) {
            bvec8 wf = *(const bvec8*)(wb + (size_t)((kk * 4 + mt) * 64 + lane) * 8);
            #pragma unroll
            for (int nt = 0; nt < 4; ++nt)
                acc[mt][nt] = __builtin_amdgcn_mfma_f32_16x16x32_bf16(wf, xb[nt], acc[mt][nt], 0, 0, 0);
        }
    }
    #pragma unroll
    for (int mt = 0; mt < 4; ++mt)
        #pragma unroll
        for (int nt = 0; nt < 4; ++nt) {
            int pt   = p0 + nt * 16 + l15;
            int col0 = h * DH_ + mt * 16 + l4 * 4;
            f32x4 fv = *(const f32x4*)(feats + (size_t)pt * C_ + col0);
            f32x4 gv = *(const f32x4*)(gamma + col0);
            f32x4 bv = *(const f32x4*)(bproj + col0);
            float has = fillcnt[pt] > 0 ? 1.f : 0.f;
            f32x4 r;
            #pragma unroll
            for (int j = 0; j < 4; ++j)
                r[j] = fv[j] + (acc[mt][nt][j] + bv[j]) * gv[j] * has;
            *(f32x4*)(out + (size_t)pt * C_ + col0) = r;
        }
}

extern "C" void kernel_launch(void* const* d_in, const int* in_sizes, int n_in,
                              void* d_out, int out_size, void* d_ws, size_t ws_size,
                              hipStream_t stream) {
    const float* feats = (const float*)d_in[0];
    const int*   gidx  = (const int*)d_in[1];
    const float* gmask = (const float*)d_in[2];
    const float* wqkv  = (const float*)d_in[3];
    const float* wproj = (const float*)d_in[4];
    const float* bproj = (const float*)d_in[5];
    const float* gamma = (const float*)d_in[6];
    float* out = (float*)d_out;

    char* ws = (char*)d_ws;
    short* wq_frag = (short*)ws;                               // 884736
    short* wp_frag = (short*)(ws + 884736);                    // 294912
    int*   fillcnt = (int*)(ws + 1179648);                     // 262144
    // MODE A layout:
    unsigned short* list = (unsigned short*)(ws + 1441792);    // 2 MiB (CAP 16)
    unsigned char* slotA = (unsigned char*)(ws + 3538944);     // 50331648
    unsigned char* qbA   = (unsigned char*)(ws + 53870592);    // 25165824
    unsigned char* kbA   = (unsigned char*)(ws + 79036416);    // 25165824
    unsigned char* vbA   = (unsigned char*)(ws + 104202240);   // 25165824 -> 129368064 total
    const size_t neededA = 129368064;
    // MODE B layout:
    unsigned char* qbB = (unsigned char*)(ws + 1441792);
    unsigned char* kbB = (unsigned char*)(ws + 26607616);
    unsigned char* vbB = (unsigned char*)(ws + 51773440);

    convw_kernel<<<(55296 + 18432 + 255) / 256, 256, 0, stream>>>(wqkv, wproj, wq_frag, wp_frag);
    (void)hipMemsetAsync(fillcnt, 0, (size_t)B_ * NMAX * sizeof(int), stream);
    fill_kernel<<<(B_ * G_ * K_ + 255) / 256, 256, 0, stream>>>(gidx, gmask, fillcnt, list);

    if (ws_size >= neededA) {
        qkv_kernel<<<(B_ * NMAX) / QKV_M, 768, QKV_LDS, stream>>>(feats, wq_frag, qbA, kbA, vbA);
        attn2_kernel<true><<<B_ * G_, 384, ATTN_LDS, stream>>>(gidx, gmask, qbA, kbA, vbA,
                                                               slotA, nullptr);
        avgproj2_kernel<<<(B_ * NMAX) / 32, 384, AP2_LDS, stream>>>(feats, fillcnt, list, slotA,
                                                                    wp_frag, bproj, gamma, out);
    } else {
        (void)hipMemsetAsync(out, 0, (size_t)B_ * NMAX * C_ * sizeof(float), stream);
        qkv_kernel<<<(B_ * NMAX) / QKV_M, 768, QKV_LDS, stream>>>(feats, wq_frag, qbB, kbB, vbB);
        attn2_kernel<false><<<B_ * G_, 384, ATTN_LDS, stream>>>(gidx, gmask, qbB, kbB, vbB,
                                                                nullptr, out);
        avgproj_kernel<<<(B_ * NMAX) / 64, 384, AP_LDS, stream>>>(feats, fillcnt, wp_frag,
                                                                  bproj, gamma, out);
    }
}